// Round 6
// baseline (59.684 us; speedup 1.0000x reference)
//
#include <hip/hip_runtime.h>
#include <math.h>

#define PI_F 3.14159265358979323846f

// ---- 16-lane sum reduction entirely on the VALU pipe via DPP ----
// xor1 = quad_perm[1,0,3,2] (0xB1), xor2 = quad_perm[2,3,0,1] (0x4E),
// then row_ror:4 (0x124) + row_ror:8 (0x128) sum the four quad-sums.
template <int CTRL>
__device__ __forceinline__ float dpp_addf(float v) {
  int p = __builtin_amdgcn_update_dpp(0, __float_as_int(v), CTRL, 0xF, 0xF, true);
  return v + __int_as_float(p);
}
__device__ __forceinline__ float red16(float v) {
  v = dpp_addf<0xB1>(v);
  v = dpp_addf<0x4E>(v);
  v = dpp_addf<0x124>(v);
  v = dpp_addf<0x128>(v);
  return v;
}

__device__ __forceinline__ void gload_lds16(const float* g, float* l) {
  __builtin_amdgcn_global_load_lds(
      (const __attribute__((address_space(1))) void*)g,
      (__attribute__((address_space(3))) void*)l, 16, 0, 0);
}

// Kernel 1: Zernike pooling. One block per (batch, rank-half): 16 ch x 256 px.
// LDS pixel-major, chunk-swizzled: float chunk (p, q) lives at slot 4p + (q^(p&3)).
// Staged by global_load_lds (linear LDS dest, pre-swizzled global source, m173).
__global__ __launch_bounds__(256, 8) void zpool_kernel(const float* __restrict__ x,
                                                       float* __restrict__ pooled) {
  const int blk = blockIdx.x;              // 0..6143
  const int b = blk / 6;
  const int half = blk - b * 6;            // 0..5
  const int rank = half >> 1;
  const int ch0 = (half & 1) * 16;
  const float* __restrict__ src = x + (size_t)b * 24576 + rank * 32 + ch0;

  __shared__ float lds[4096];              // 256 px * 16 ch = 16 KB
  const int t = threadIdx.x;
  const int lane = t & 63;
  const int w = t >> 6;                    // wave 0..3

  // Stage: 4 instrs/thread; instr covers chunk slots [(w*4+it)*64 .. +63].
#pragma unroll
  for (int it = 0; it < 4; ++it) {
    const int s = (w * 4 + it) * 64 + lane;          // chunk slot
    const int p = s >> 2;                            // pixel
    const int q = (s & 3) ^ (p & 3);                 // source chunk (swizzle inverse)
    gload_lds16(src + p * 96 + q * 4, &lds[(w * 4 + it) * 256]);
  }
  __syncthreads();

  const int sub = lane >> 4;               // 0..3
  const int sl = lane & 15;                // pixel column x
  const int ch = w * 4 + sub;              // local channel 0..15
  const float X = -1.0f + (float)sl * (2.0f / 15.0f);  // lane-constant

  // Transpose-read: word = 16p + 4*(w^(p&3)) + sub, p = sl + 16k  (4-way banked)
  const int rbase = 16 * sl + 4 * (w ^ (sl & 3)) + sub;
  float f[16];
#pragma unroll
  for (int k = 0; k < 16; ++k) f[k] = lds[rbase + 256 * k];

  // Pass 1: centroid. X lane-const -> sx = X*s0; Y varies per k.
  float s0 = 0.0f, sy = 0.0f;
#pragma unroll
  for (int k = 0; k < 16; ++k) {
    const float Y = -1.0f + (float)k * (2.0f / 15.0f);
    s0 += f[k];
    sy = fmaf(f[k], Y, sy);
  }
  float sx = X * s0;
  s0 = red16(s0); sx = red16(sx); sy = red16(sy);
  const float invm = 1.0f / (s0 + 1e-6f);
  const float cx = sx * invm;
  const float cy = sy * invm;

  const float Xs = X - cx;
  const float Xs2 = Xs * Xs;
  const float lim = 1.0f - Xs2;            // mask: Ys^2 <= 1 - Xs^2

  // Pass 2: only 4 accumulators: m0=Sg, m1=Sg*Ys, m2=Sg*Ys^2, m3=Sg*Ys^3.
  float m0 = 0, m1 = 0, m2 = 0, m3 = 0;
#pragma unroll
  for (int k = 0; k < 16; ++k) {
    const float Y = -1.0f + (float)k * (2.0f / 15.0f);
    const float Ys = Y - cy;
    const float Ys2 = Ys * Ys;
    const float g = (Ys2 <= lim) ? f[k] : 0.0f;
    const float gy = g * Ys;
    m0 += g;
    m1 += gy;
    m2 = fmaf(gy, Ys, m2);
    m3 = fmaf(gy, Ys2, m3);
  }

  // Lane-local derivation of the 10 moment sums (Xs is lane-constant):
  const float t3 = fmaf(3.0f, Xs2, -2.0f);           // 3Xs^2 - 2
  float a0 = m0;
  float a1 = Xs * m0;
  float b1 = m1;
  float a2 = fmaf(2.0f, m2, fmaf(2.0f, Xs2, -1.0f) * m0);
  float a3 = fmaf(Xs2, m0, -m2);
  float b3 = 2.0f * Xs * m1;
  float a4 = Xs * fmaf(3.0f, m2, t3 * m0);
  float b4 = fmaf(3.0f, m3, t3 * m1);
  float a5 = Xs * fmaf(Xs2, m0, -3.0f * m2);
  float b5 = fmaf(3.0f * Xs2, m1, -m3);

  a0 = red16(a0); a1 = red16(a1); b1 = red16(b1); a2 = red16(a2); a3 = red16(a3);
  b3 = red16(b3); a4 = red16(a4); b4 = red16(b4); a5 = red16(a5); b5 = red16(b5);

  if (sl == 0) {
    float* po = pooled + (size_t)b * 576 + rank * 192 + ch0 + ch;
    const float INV = 1.0f / 65536.0f;     // (1/256)^2 for the squared means
    po[0]   = (1.0f / PI_F) * sqrtf(a0 * a0 * INV + 1e-12f);
    po[32]  = (2.0f / PI_F) * sqrtf(fmaf(a1, a1, b1 * b1) * INV + 1e-12f);
    po[64]  = (3.0f / PI_F) * sqrtf(a2 * a2 * INV + 1e-12f);
    po[96]  = (3.0f / PI_F) * sqrtf(fmaf(a3, a3, b3 * b3) * INV + 1e-12f);
    po[128] = (4.0f / PI_F) * sqrtf(fmaf(a4, a4, b4 * b4) * INV + 1e-12f);
    po[160] = (4.0f / PI_F) * sqrtf(fmaf(a5, a5, b5 * b5) * INV + 1e-12f);
  }
}

// Kernel 2: BN stats, coalesced. 9 blocks x 1024 thr; block owns 64 features;
// wave w accumulates rows w, w+16, ... (64 rows); lane owns one feature.
__global__ __launch_bounds__(1024) void bn_stats_kernel(const float* __restrict__ pooled,
                                                        const float* __restrict__ gamma,
                                                        const float* __restrict__ beta,
                                                        float* __restrict__ a,
                                                        float* __restrict__ c) {
  const int f0 = blockIdx.x * 64;          // 0,64,...,512
  const int t = threadIdx.x;
  const int w = t >> 6, lane = t & 63;
  const float* p = pooled + f0 + lane;
  float s = 0.0f, sq = 0.0f;
  for (int row = w; row < 1024; row += 16) {
    const float v = p[(size_t)row * 576];  // 256B coalesced per wave-instr
    s += v;
    sq = fmaf(v, v, sq);
  }
  __shared__ float ls[16][64];
  __shared__ float lq[16][64];
  ls[w][lane] = s;
  lq[w][lane] = sq;
  __syncthreads();
  if (t < 64) {
    float S = 0.0f, Q = 0.0f;
#pragma unroll
    for (int i = 0; i < 16; ++i) { S += ls[i][t]; Q += lq[i][t]; }
    const float mean = S * (1.0f / 1024.0f);
    const float var = fmaf(-mean, mean, Q * (1.0f / 1024.0f));  // biased var
    const float istd = rsqrtf(var + 1e-5f);
    const float av = gamma[f0 + t] * istd;
    a[f0 + t] = av;
    c[f0 + t] = fmaf(-mean, av, beta[f0 + t]);
  }
}

// Kernel 3: z = pooled*a + c, then z @ W^T + b. One wave per batch row.
__global__ __launch_bounds__(64) void head_kernel(const float* __restrict__ pooled,
                                                  const float* __restrict__ a,
                                                  const float* __restrict__ c,
                                                  const float* __restrict__ Wl,
                                                  const float* __restrict__ bl,
                                                  float* __restrict__ out) {
  const int row = blockIdx.x;     // 0..1023
  const int lane = threadIdx.x;   // 0..63
  const float* pr = pooled + (size_t)row * 576;
  float acc0 = 0, acc1 = 0, acc2 = 0, acc3 = 0, acc4 = 0;
  float acc5 = 0, acc6 = 0, acc7 = 0, acc8 = 0, acc9 = 0;
#pragma unroll
  for (int j = 0; j < 9; ++j) {
    const int k = lane + 64 * j;
    const float z = fmaf(pr[k], a[k], c[k]);
    acc0 = fmaf(z, Wl[0 * 576 + k], acc0);
    acc1 = fmaf(z, Wl[1 * 576 + k], acc1);
    acc2 = fmaf(z, Wl[2 * 576 + k], acc2);
    acc3 = fmaf(z, Wl[3 * 576 + k], acc3);
    acc4 = fmaf(z, Wl[4 * 576 + k], acc4);
    acc5 = fmaf(z, Wl[5 * 576 + k], acc5);
    acc6 = fmaf(z, Wl[6 * 576 + k], acc6);
    acc7 = fmaf(z, Wl[7 * 576 + k], acc7);
    acc8 = fmaf(z, Wl[8 * 576 + k], acc8);
    acc9 = fmaf(z, Wl[9 * 576 + k], acc9);
  }
#pragma unroll
  for (int m = 1; m < 64; m <<= 1) {
    acc0 += __shfl_xor(acc0, m); acc1 += __shfl_xor(acc1, m);
    acc2 += __shfl_xor(acc2, m); acc3 += __shfl_xor(acc3, m);
    acc4 += __shfl_xor(acc4, m); acc5 += __shfl_xor(acc5, m);
    acc6 += __shfl_xor(acc6, m); acc7 += __shfl_xor(acc7, m);
    acc8 += __shfl_xor(acc8, m); acc9 += __shfl_xor(acc9, m);
  }
  if (lane == 0) {
    float* o = out + (size_t)row * 10;
    o[0] = acc0 + bl[0]; o[1] = acc1 + bl[1]; o[2] = acc2 + bl[2];
    o[3] = acc3 + bl[3]; o[4] = acc4 + bl[4]; o[5] = acc5 + bl[5];
    o[6] = acc6 + bl[6]; o[7] = acc7 + bl[7]; o[8] = acc8 + bl[8];
    o[9] = acc9 + bl[9];
  }
}

extern "C" void kernel_launch(void* const* d_in, const int* in_sizes, int n_in,
                              void* d_out, int out_size, void* d_ws, size_t ws_size,
                              hipStream_t stream) {
  const float* x     = (const float*)d_in[0];
  const float* gamma = (const float*)d_in[1];
  const float* beta  = (const float*)d_in[2];
  const float* Wl    = (const float*)d_in[3];
  const float* bl    = (const float*)d_in[4];
  float* out = (float*)d_out;

  float* pooled = (float*)d_ws;            // 1024*576 floats
  float* a = pooled + 576 * 1024;          // 576 floats
  float* c = a + 576;                      // 576 floats

  zpool_kernel<<<6144, 256, 0, stream>>>(x, pooled);
  bn_stats_kernel<<<9, 1024, 0, stream>>>(pooled, gamma, beta, a, c);
  head_kernel<<<1024, 64, 0, stream>>>(pooled, a, c, Wl, bl, out);
}

// Round 7
// 53.853 us; speedup vs baseline: 1.1083x; 1.1083x over previous
//
#include <hip/hip_runtime.h>
#include <math.h>

#define PI_F 3.14159265358979323846f
typedef float floatx4 __attribute__((ext_vector_type(4)));

// ---- 16-lane sum reduction entirely on the VALU pipe via DPP ----
// xor1 = quad_perm[1,0,3,2] (0xB1), xor2 = quad_perm[2,3,0,1] (0x4E),
// then row_ror:4 (0x124) + row_ror:8 (0x128) sum the four quad-sums.
template <int CTRL>
__device__ __forceinline__ float dpp_addf(float v) {
  int p = __builtin_amdgcn_update_dpp(0, __float_as_int(v), CTRL, 0xF, 0xF, true);
  return v + __int_as_float(p);
}
__device__ __forceinline__ float red16(float v) {
  v = dpp_addf<0xB1>(v);
  v = dpp_addf<0x4E>(v);
  v = dpp_addf<0x124>(v);
  v = dpp_addf<0x128>(v);
  return v;
}
__device__ __forceinline__ floatx4 red16v(floatx4 v) {
  floatx4 r;
#pragma unroll
  for (int c = 0; c < 4; ++c) r[c] = red16(v[c]);
  return r;
}

// Kernel 1: Zernike pooling, NO LDS / NO barriers.
// 16 lanes own one (b, rank, ch-quad): lane sl holds pixels p = sl+16k as float4
// (4 channels) in registers. Global float4 loads: per wave-instr 16 rows x 64B
// contiguous = 1KB fully coalesced. All reductions are 16-lane DPP (VALU pipe).
__global__ __launch_bounds__(256, 2) void zpool_kernel(const float* __restrict__ x,
                                                       float* __restrict__ pooled) {
  const int t = threadIdx.x;
  const int grp = blockIdx.x * 16 + (t >> 4);   // global group 0..24575
  const int sl = t & 15;                        // pixel column
  const int cq = grp & 7;                       // channel quad 0..7
  const int rk = grp >> 3;                      // b*3 + rank
  const int rank = rk % 3;
  const int b = rk / 3;
  const float* __restrict__ src = x + (size_t)b * 24576 + rank * 32 + cq * 4;
  const float X = -1.0f + (float)sl * (2.0f / 15.0f);   // lane-constant

  floatx4 f[16];
#pragma unroll
  for (int k = 0; k < 16; ++k)
    f[k] = *reinterpret_cast<const floatx4*>(src + (sl + 16 * k) * 96);

  // Pass 1: centroid sums (per channel = per component). sx = X*s0 (X lane-const).
  floatx4 s0 = {0, 0, 0, 0}, sy = {0, 0, 0, 0};
#pragma unroll
  for (int k = 0; k < 16; ++k) {
    const float Y = -1.0f + (float)k * (2.0f / 15.0f);
    s0 += f[k];
    sy += f[k] * Y;
  }
  floatx4 sx = s0 * X;
  s0 = red16v(s0); sx = red16v(sx); sy = red16v(sy);
  floatx4 invm;
#pragma unroll
  for (int c = 0; c < 4; ++c) invm[c] = 1.0f / (s0[c] + 1e-6f);
  const floatx4 cx = sx * invm;
  const floatx4 cy = sy * invm;

  const floatx4 Xs = X - cx;
  const floatx4 Xs2 = Xs * Xs;
  const floatx4 lim = 1.0f - Xs2;               // mask: Ys^2 <= 1 - Xs^2

  // Pass 2: 4 accumulators per channel: m_j = sum g * Ys^j, j=0..3.
  floatx4 m0 = {0,0,0,0}, m1 = {0,0,0,0}, m2 = {0,0,0,0}, m3 = {0,0,0,0};
#pragma unroll
  for (int k = 0; k < 16; ++k) {
    const float Y = -1.0f + (float)k * (2.0f / 15.0f);
    const floatx4 Ys = Y - cy;
    const floatx4 Ys2 = Ys * Ys;
    floatx4 g;
#pragma unroll
    for (int c = 0; c < 4; ++c) g[c] = (Ys2[c] <= lim[c]) ? f[k][c] : 0.0f;
    const floatx4 gy = g * Ys;
    m0 += g;
    m1 += gy;
    m2 += gy * Ys;
    m3 += gy * Ys2;
  }

  // Reduce the 10 raw sums S_ij = sum_lanes Xs^i * m_j; derive invariants after.
  const floatx4 Xs3 = Xs2 * Xs;
  floatx4 S00 = red16v(m0);
  floatx4 S10 = red16v(Xs * m0);
  floatx4 S20 = red16v(Xs2 * m0);
  floatx4 S30 = red16v(Xs3 * m0);
  floatx4 S01 = red16v(m1);
  floatx4 S11 = red16v(Xs * m1);
  floatx4 S21 = red16v(Xs2 * m1);
  floatx4 S02 = red16v(m2);
  floatx4 S12 = red16v(Xs * m2);
  floatx4 S03 = red16v(m3);

  if (sl == 0) {
    const floatx4 a0 = S00;
    const floatx4 a1 = S10, b1 = S01;
    const floatx4 a2 = 2.0f * (S20 + S02) - S00;
    const floatx4 a3 = S20 - S02, b3 = 2.0f * S11;
    const floatx4 a4 = 3.0f * (S30 + S12) - 2.0f * S10;
    const floatx4 b4 = 3.0f * (S21 + S03) - 2.0f * S01;
    const floatx4 a5 = S30 - 3.0f * S12;
    const floatx4 b5 = 3.0f * S21 - S03;
    const float INV = 1.0f / 65536.0f;          // (1/256)^2 for the squared means
    float* po = pooled + (size_t)b * 576 + rank * 192 + cq * 4;
#pragma unroll
    for (int c = 0; c < 4; ++c) {
      po[c]       = (1.0f / PI_F) * sqrtf(a0[c] * a0[c] * INV + 1e-12f);
      po[32 + c]  = (2.0f / PI_F) * sqrtf(fmaf(a1[c], a1[c], b1[c] * b1[c]) * INV + 1e-12f);
      po[64 + c]  = (3.0f / PI_F) * sqrtf(a2[c] * a2[c] * INV + 1e-12f);
      po[96 + c]  = (3.0f / PI_F) * sqrtf(fmaf(a3[c], a3[c], b3[c] * b3[c]) * INV + 1e-12f);
      po[128 + c] = (4.0f / PI_F) * sqrtf(fmaf(a4[c], a4[c], b4[c] * b4[c]) * INV + 1e-12f);
      po[160 + c] = (4.0f / PI_F) * sqrtf(fmaf(a5[c], a5[c], b5[c] * b5[c]) * INV + 1e-12f);
    }
  }
}

// Kernel 2: BN stats, coalesced. 9 blocks x 1024 thr; block owns 64 features;
// wave w accumulates rows w, w+16, ... (64 rows); lane owns one feature.
__global__ __launch_bounds__(1024) void bn_stats_kernel(const float* __restrict__ pooled,
                                                        const float* __restrict__ gamma,
                                                        const float* __restrict__ beta,
                                                        float* __restrict__ a,
                                                        float* __restrict__ c) {
  const int f0 = blockIdx.x * 64;          // 0,64,...,512
  const int t = threadIdx.x;
  const int w = t >> 6, lane = t & 63;
  const float* p = pooled + f0 + lane;
  float s = 0.0f, sq = 0.0f;
  for (int row = w; row < 1024; row += 16) {
    const float v = p[(size_t)row * 576];  // 256B coalesced per wave-instr
    s += v;
    sq = fmaf(v, v, sq);
  }
  __shared__ float ls[16][64];
  __shared__ float lq[16][64];
  ls[w][lane] = s;
  lq[w][lane] = sq;
  __syncthreads();
  if (t < 64) {
    float S = 0.0f, Q = 0.0f;
#pragma unroll
    for (int i = 0; i < 16; ++i) { S += ls[i][t]; Q += lq[i][t]; }
    const float mean = S * (1.0f / 1024.0f);
    const float var = fmaf(-mean, mean, Q * (1.0f / 1024.0f));  // biased var
    const float istd = rsqrtf(var + 1e-5f);
    const float av = gamma[f0 + t] * istd;
    a[f0 + t] = av;
    c[f0 + t] = fmaf(-mean, av, beta[f0 + t]);
  }
}

// Kernel 3: z = pooled*a + c, then z @ W^T + b. One wave per batch row.
__global__ __launch_bounds__(64) void head_kernel(const float* __restrict__ pooled,
                                                  const float* __restrict__ a,
                                                  const float* __restrict__ c,
                                                  const float* __restrict__ Wl,
                                                  const float* __restrict__ bl,
                                                  float* __restrict__ out) {
  const int row = blockIdx.x;     // 0..1023
  const int lane = threadIdx.x;   // 0..63
  const float* pr = pooled + (size_t)row * 576;
  float acc0 = 0, acc1 = 0, acc2 = 0, acc3 = 0, acc4 = 0;
  float acc5 = 0, acc6 = 0, acc7 = 0, acc8 = 0, acc9 = 0;
#pragma unroll
  for (int j = 0; j < 9; ++j) {
    const int k = lane + 64 * j;
    const float z = fmaf(pr[k], a[k], c[k]);
    acc0 = fmaf(z, Wl[0 * 576 + k], acc0);
    acc1 = fmaf(z, Wl[1 * 576 + k], acc1);
    acc2 = fmaf(z, Wl[2 * 576 + k], acc2);
    acc3 = fmaf(z, Wl[3 * 576 + k], acc3);
    acc4 = fmaf(z, Wl[4 * 576 + k], acc4);
    acc5 = fmaf(z, Wl[5 * 576 + k], acc5);
    acc6 = fmaf(z, Wl[6 * 576 + k], acc6);
    acc7 = fmaf(z, Wl[7 * 576 + k], acc7);
    acc8 = fmaf(z, Wl[8 * 576 + k], acc8);
    acc9 = fmaf(z, Wl[9 * 576 + k], acc9);
  }
#pragma unroll
  for (int m = 1; m < 64; m <<= 1) {
    acc0 += __shfl_xor(acc0, m); acc1 += __shfl_xor(acc1, m);
    acc2 += __shfl_xor(acc2, m); acc3 += __shfl_xor(acc3, m);
    acc4 += __shfl_xor(acc4, m); acc5 += __shfl_xor(acc5, m);
    acc6 += __shfl_xor(acc6, m); acc7 += __shfl_xor(acc7, m);
    acc8 += __shfl_xor(acc8, m); acc9 += __shfl_xor(acc9, m);
  }
  if (lane == 0) {
    float* o = out + (size_t)row * 10;
    o[0] = acc0 + bl[0]; o[1] = acc1 + bl[1]; o[2] = acc2 + bl[2];
    o[3] = acc3 + bl[3]; o[4] = acc4 + bl[4]; o[5] = acc5 + bl[5];
    o[6] = acc6 + bl[6]; o[7] = acc7 + bl[7]; o[8] = acc8 + bl[8];
    o[9] = acc9 + bl[9];
  }
}

extern "C" void kernel_launch(void* const* d_in, const int* in_sizes, int n_in,
                              void* d_out, int out_size, void* d_ws, size_t ws_size,
                              hipStream_t stream) {
  const float* x     = (const float*)d_in[0];
  const float* gamma = (const float*)d_in[1];
  const float* beta  = (const float*)d_in[2];
  const float* Wl    = (const float*)d_in[3];
  const float* bl    = (const float*)d_in[4];
  float* out = (float*)d_out;

  float* pooled = (float*)d_ws;            // 1024*576 floats
  float* a = pooled + 576 * 1024;          // 576 floats
  float* c = a + 576;                      // 576 floats

  zpool_kernel<<<1536, 256, 0, stream>>>(x, pooled);
  bn_stats_kernel<<<9, 1024, 0, stream>>>(pooled, gamma, beta, a, c);
  head_kernel<<<1024, 64, 0, stream>>>(pooled, a, c, Wl, bl, out);
}